// Round 3
// baseline (608.177 us; speedup 1.0000x reference)
//
#include <hip/hip_runtime.h>
#include <hip/hip_bf16.h>
#include <stdint.h>

#define NTOK 1560
#define DIMM 1536
#define NQKV 4608
#define NHEADS 12
#define HDIM 128
#define FRAME 1560
#define CURS 9360
#define LVAL 10920
#define LPAD 10944
#define QPAD 1792
#define MPAD 1664
#define KSPL 3
#define TPS 57
#define RSCALE 0.088388347648318447f

typedef __attribute__((ext_vector_type(4))) float f32x4;
typedef __attribute__((ext_vector_type(8))) short s16x8;
typedef __attribute__((ext_vector_type(4))) short s16x4;

__device__ __forceinline__ short f2bf(float f){
  union { float f; uint32_t u; } v; v.f = f;
  uint32_t r = v.u + 0x7fffu + ((v.u >> 16) & 1u);
  return (short)(r >> 16);
}
__device__ __forceinline__ uint32_t pack2(float lo, float hi){
  return ((uint32_t)(uint16_t)f2bf(hi) << 16) | (uint32_t)(uint16_t)f2bf(lo);
}

#define GLOAD16(srcp, dstp) __builtin_amdgcn_global_load_lds( \
  (const __attribute__((address_space(1))) void*)(srcp), \
  (__attribute__((address_space(3))) void*)(dstp), 16, 0, 0)

__device__ __forceinline__ f32x4 mfma16x16x16bf(s16x4 a, s16x4 b, f32x4 c){
#if __has_builtin(__builtin_amdgcn_mfma_f32_16x16x16bf16_1k)
  return __builtin_amdgcn_mfma_f32_16x16x16bf16_1k(a, b, c, 0, 0, 0);
#else
  asm volatile("v_mfma_f32_16x16x16_bf16 %0, %1, %2, %0" : "+v"(c) : "v"(a), "v"(b));
  return c;
#endif
}

// ---------------- kernel 1: convert x + weights to bf16 ----------------
__global__ void k_conv_misc(const float* __restrict__ x, const float* __restrict__ wq,
                            const float* __restrict__ wk, const float* __restrict__ wv,
                            const float* __restrict__ wo,
                            short* __restrict__ xb, short* __restrict__ wqkv, short* __restrict__ wob){
  const int64_t n_xb = (int64_t)MPAD*DIMM/4;
  const int64_t n_w  = (int64_t)DIMM*DIMM/4;
  const int64_t total = n_xb + 4*n_w;
  for (int64_t i = (int64_t)blockIdx.x*blockDim.x + threadIdx.x; i < total;
       i += (int64_t)gridDim.x*blockDim.x){
    if (i < n_xb){
      int64_t idx = i*4;
      int row = (int)(idx / DIMM);
      s16x4 o;
      if (row < NTOK){
        float4 v = *(const float4*)(x + idx);
        o.x=f2bf(v.x); o.y=f2bf(v.y); o.z=f2bf(v.z); o.w=f2bf(v.w);
      } else { o.x=0; o.y=0; o.z=0; o.w=0; }
      *(s16x4*)(xb + idx) = o;
    } else {
      int64_t j = i - n_xb;
      int which = (int)(j / n_w);
      int64_t off = (j % n_w)*4;
      const float* src = (which==0)?wq:(which==1)?wk:(which==2)?wv:wo;
      float4 v = *(const float4*)(src + off);
      s16x4 o; o.x=f2bf(v.x); o.y=f2bf(v.y); o.z=f2bf(v.z); o.w=f2bf(v.w);
      short* dst = (which<3) ? (wqkv + (int64_t)which*DIMM*DIMM + off) : (wob + off);
      *(s16x4*)dst = o;
    }
  }
}

// ---------------- kernel 2: cache_k -> bf16 [head][key][128] ----------------
__global__ void k_conv_k(const float* __restrict__ ck, short* __restrict__ Kb){
  const int64_t total = (int64_t)LPAD*DIMM/4;
  for (int64_t i = (int64_t)blockIdx.x*blockDim.x + threadIdx.x; i < total;
       i += (int64_t)gridDim.x*blockDim.x){
    int64_t idx = i*4;
    int key = (int)(idx / DIMM);
    if (key >= CURS && key < LVAL) continue;   // epilogue writes these
    int hd = (int)(idx % DIMM);
    int h = hd >> 7, d = hd & 127;
    s16x4 o;
    if (key < CURS){
      float4 v = *(const float4*)(ck + (int64_t)key*DIMM + hd);
      o.x=f2bf(v.x); o.y=f2bf(v.y); o.z=f2bf(v.z); o.w=f2bf(v.w);
    } else { o.x=0; o.y=0; o.z=0; o.w=0; }
    *(s16x4*)(Kb + ((int64_t)h*LPAD + key)*HDIM + d) = o;
  }
}

// ---------------- kernel 3/8: bf16 GEMM  C[M][N] = A[M][K] * B[N][K]^T (+bias) ----------------
__global__ __launch_bounds__(256) void k_gemm(const short* __restrict__ A, const short* __restrict__ B,
                       float* __restrict__ C, const float* __restrict__ bias,
                       int N, int K, int Mvalid){
  __shared__ short As[128*64];
  __shared__ short Bs[128*64];
  const int t = threadIdx.x;
  const int lane = t & 63;
  const int w = t >> 6, wm = w >> 1, wn = w & 1;
  const int l15 = lane & 15, g = lane >> 4;
  const int m0 = blockIdx.y * 128, n0 = blockIdx.x * 128;
  f32x4 acc[4][4] = {};
  const int r = t >> 3, c = t & 7;
  const int nkt = K >> 6;
  for (int kt = 0; kt < nkt; ++kt){
    #pragma unroll
    for (int i = 0; i < 4; ++i){
      int rr = r + 32*i;
      int cs = (c*16) ^ ((rr & 7) << 4);
      GLOAD16((const char*)(A + (int64_t)(m0+rr)*K + kt*64) + cs, (char*)As + t*16 + i*4096);
    }
    #pragma unroll
    for (int i = 0; i < 4; ++i){
      int rr = r + 32*i;
      int cs = (c*16) ^ ((rr & 7) << 4);
      GLOAD16((const char*)(B + (int64_t)(n0+rr)*K + kt*64) + cs, (char*)Bs + t*16 + i*4096);
    }
    __syncthreads();
    #pragma unroll
    for (int kk = 0; kk < 2; ++kk){
      s16x8 af[4], bfr[4];
      #pragma unroll
      for (int fm = 0; fm < 4; ++fm){
        int row = wm*64 + fm*16 + l15;
        int b = (kk*64 + g*16) ^ ((row & 7) << 4);
        af[fm] = *(const s16x8*)((const char*)As + row*128 + b);
      }
      #pragma unroll
      for (int fn = 0; fn < 4; ++fn){
        int row = wn*64 + fn*16 + l15;
        int b = (kk*64 + g*16) ^ ((row & 7) << 4);
        bfr[fn] = *(const s16x8*)((const char*)Bs + row*128 + b);
      }
      #pragma unroll
      for (int fm = 0; fm < 4; ++fm)
        #pragma unroll
        for (int fn = 0; fn < 4; ++fn)
          acc[fm][fn] = __builtin_amdgcn_mfma_f32_16x16x32_bf16(af[fm], bfr[fn], acc[fm][fn], 0, 0, 0);
    }
    __syncthreads();
  }
  #pragma unroll
  for (int fm = 0; fm < 4; ++fm){
    #pragma unroll
    for (int fn = 0; fn < 4; ++fn){
      int n = n0 + wn*64 + fn*16 + l15;
      float bvv = bias ? bias[n] : 0.0f;
      #pragma unroll
      for (int rr = 0; rr < 4; ++rr){
        int m = m0 + wm*64 + fm*16 + g*4 + rr;
        if (m < Mvalid) C[(int64_t)m*N + n] = acc[fm][fn][rr] + bvv;
      }
    }
  }
}

// ---------------- kernel 4: rmsnorm + rope + pack ----------------
__global__ __launch_bounds__(256) void k_epi(const float* __restrict__ qkv,
      const float* __restrict__ bq, const float* __restrict__ bk, const float* __restrict__ bv,
      const float* __restrict__ gq, const float* __restrict__ gk,
      const float* __restrict__ fcos, const float* __restrict__ fsin,
      short* __restrict__ Qb, short* __restrict__ Kb, short* __restrict__ Vtmp){
  const int tok = blockIdx.x;
  const int tid = threadIdx.x;
  const float* row = qkv + (int64_t)tok*NQKV;
  float sq = 0.f, sk = 0.f;
  for (int i = tid; i < DIMM; i += 256){
    float a = row[i] + bq[i]; sq += a*a;
    float b = row[DIMM + i] + bk[i]; sk += b*b;
  }
  #pragma unroll
  for (int o = 32; o > 0; o >>= 1){ sq += __shfl_xor(sq, o); sk += __shfl_xor(sk, o); }
  __shared__ float red[2][4];
  if ((tid & 63) == 0){ red[0][tid>>6] = sq; red[1][tid>>6] = sk; }
  __syncthreads();
  sq = red[0][0] + red[0][1] + red[0][2] + red[0][3];
  sk = red[1][0] + red[1][1] + red[1][2] + red[1][3];
  const float rq = rsqrtf(sq * (1.0f/DIMM) + 1e-6f);
  const float rk = rsqrtf(sk * (1.0f/DIMM) + 1e-6f);
  const int hh = tok / 52;             // t%FRAME == t here
  const int ww = tok % 52;
  const int rowf = (CURS / FRAME) + (tok / FRAME);
  for (int p = tid; p < DIMM/2; p += 256){
    int h = p >> 6, cp = p & 63;
    int trow = (cp < 22) ? rowf : (cp < 43 ? hh : ww);
    float cv = fcos[trow*64 + cp], sv = fsin[trow*64 + cp];
    int base = h*HDIM + 2*cp;
    float q0 = (row[base] + bq[base]) * rq * gq[base];
    float q1 = (row[base+1] + bq[base+1]) * rq * gq[base+1];
    float k0 = (row[DIMM+base] + bk[base]) * rk * gk[base];
    float k1 = (row[DIMM+base+1] + bk[base+1]) * rk * gk[base+1];
    float v0 = row[2*DIMM+base] + bv[base];
    float v1 = row[2*DIMM+base+1] + bv[base+1];
    *(uint32_t*)(Qb + ((int64_t)h*QPAD + tok)*HDIM + 2*cp) =
        pack2((q0*cv - q1*sv)*RSCALE, (q0*sv + q1*cv)*RSCALE);
    *(uint32_t*)(Kb + ((int64_t)h*LPAD + CURS + tok)*HDIM + 2*cp) =
        pack2(k0*cv - k1*sv, k0*sv + k1*cv);
    *(uint32_t*)(Vtmp + (int64_t)tok*DIMM + base) = pack2(v0, v1);
  }
}

// ---------------- kernel 5: V -> bf16 transposed [head][d][key] ----------------
__global__ __launch_bounds__(256) void k_conv_v(const float* __restrict__ cvp, const short* __restrict__ Vtmp,
                                                short* __restrict__ Vt){
  __shared__ short lds[64][130];
  const int kb = blockIdx.x, h = blockIdx.y;
  const int k0 = kb*64;
  const int t = threadIdx.x;
  #pragma unroll
  for (int i = 0; i < 8; ++i){
    int idx = i*256 + t;
    int key = idx >> 5, d4 = (idx & 31) * 4;
    int gkey = k0 + key;
    s16x4 o;
    if (gkey < CURS){
      float4 v = *(const float4*)(cvp + (int64_t)gkey*DIMM + h*HDIM + d4);
      o.x=f2bf(v.x); o.y=f2bf(v.y); o.z=f2bf(v.z); o.w=f2bf(v.w);
    } else if (gkey < LVAL){
      o = *(const s16x4*)(Vtmp + (int64_t)(gkey-CURS)*DIMM + h*HDIM + d4);
    } else { o.x=0; o.y=0; o.z=0; o.w=0; }
    lds[key][d4] = o.x; lds[key][d4+1] = o.y; lds[key][d4+2] = o.z; lds[key][d4+3] = o.w;
  }
  __syncthreads();
  #pragma unroll
  for (int i = 0; i < 16; ++i){
    int idx = i*256 + t;
    int d = idx >> 5, k2 = (idx & 31)*2;
    uint32_t vp = ((uint32_t)(uint16_t)lds[k2+1][d] << 16) | (uint32_t)(uint16_t)lds[k2][d];
    *(uint32_t*)(Vt + ((int64_t)h*HDIM + d)*LPAD + k0 + k2) = vp;
  }
}

// ---------------- kernel 6: flash attention (swapped QK^T, split-K) ----------------
__global__ __launch_bounds__(512) void k_attn(const short* __restrict__ Qb, const short* __restrict__ Kb,
        const short* __restrict__ Vt, float* __restrict__ OPT,
        float* __restrict__ Mb, float* __restrict__ Lb){
  __shared__ short ldsK[64*128];   // [key][d], swizzled
  __shared__ short ldsV[128*64];   // [d][key], swizzled
  const int qb = blockIdx.x, sp = blockIdx.y, h = blockIdx.z;
  const int t = threadIdx.x, lane = t & 63, w = t >> 6;
  const int l15 = lane & 15, g = lane >> 4;
  const int qbase = qb*256 + w*32;
  s16x8 qf[2][4];
  #pragma unroll
  for (int fq = 0; fq < 2; ++fq)
    #pragma unroll
    for (int kk = 0; kk < 4; ++kk){
      int q = qbase + fq*16 + l15;
      qf[fq][kk] = *(const s16x8*)(Qb + ((int64_t)h*QPAD + q)*HDIM + kk*32 + g*8);
    }
  f32x4 acc[8][2] = {};
  float m_[2] = {-1e30f, -1e30f};
  float l_[2] = {0.f, 0.f};
  const int rK = t >> 4, cK = t & 15;
  const int rV = t >> 3, cV = t & 7;
  for (int tl = sp*TPS; tl < sp*TPS + TPS; ++tl){
    const int k0 = tl*64;
    #pragma unroll
    for (int i = 0; i < 2; ++i){
      int rr = rK + 32*i;
      int cs = (cK*16) ^ ((rr & 15) << 4);
      GLOAD16((const char*)(Kb + ((int64_t)h*LPAD + k0 + rr)*HDIM) + cs, (char*)ldsK + t*16 + i*8192);
    }
    #pragma unroll
    for (int i = 0; i < 2; ++i){
      int dd = rV + 64*i;
      int cs = (cV*16) ^ ((dd & 7) << 4);
      GLOAD16((const char*)(Vt + ((int64_t)h*HDIM + dd)*LPAD + k0) + cs, (char*)ldsV + t*16 + i*8192);
    }
    __syncthreads();
    // S^T = K @ Q^T : D[key][q]
    f32x4 sa[4][2] = {};
    #pragma unroll
    for (int fk = 0; fk < 4; ++fk){
      s16x8 kf[4];
      #pragma unroll
      for (int kk = 0; kk < 4; ++kk){
        int rowk = fk*16 + l15;
        int b = (kk*64 + g*16) ^ ((rowk & 15) << 4);
        kf[kk] = *(const s16x8*)((const char*)ldsK + rowk*256 + b);
      }
      #pragma unroll
      for (int fq = 0; fq < 2; ++fq)
        #pragma unroll
        for (int kk = 0; kk < 4; ++kk)
          sa[fk][fq] = __builtin_amdgcn_mfma_f32_16x16x32_bf16(kf[kk], qf[fq][kk], sa[fk][fq], 0, 0, 0);
    }
    const bool tail = (k0 + 64 > LVAL);
    s16x4 pf[4][2];
    float rs[2];
    #pragma unroll
    for (int fq = 0; fq < 2; ++fq){
      if (tail){
        #pragma unroll
        for (int fk = 0; fk < 4; ++fk)
          #pragma unroll
          for (int rr = 0; rr < 4; ++rr)
            if (k0 + fk*16 + g*4 + rr >= LVAL) sa[fk][fq][rr] = -1e30f;
      }
      float vm = -1e30f;
      #pragma unroll
      for (int fk = 0; fk < 4; ++fk)
        #pragma unroll
        for (int rr = 0; rr < 4; ++rr) vm = fmaxf(vm, sa[fk][fq][rr]);
      vm = fmaxf(vm, __shfl_xor(vm, 16));
      vm = fmaxf(vm, __shfl_xor(vm, 32));
      float mn = fmaxf(m_[fq], vm);
      rs[fq] = __expf(m_[fq] - mn);
      m_[fq] = mn;
      float ps = 0.f;
      #pragma unroll
      for (int fk = 0; fk < 4; ++fk){
        float p0 = __expf(sa[fk][fq][0] - mn);
        float p1 = __expf(sa[fk][fq][1] - mn);
        float p2 = __expf(sa[fk][fq][2] - mn);
        float p3 = __expf(sa[fk][fq][3] - mn);
        ps += (p0+p1)+(p2+p3);
        s16x4 pk; pk.x=f2bf(p0); pk.y=f2bf(p1); pk.z=f2bf(p2); pk.w=f2bf(p3);
        pf[fk][fq] = pk;
      }
      l_[fq] = l_[fq]*rs[fq] + ps;
    }
    #pragma unroll
    for (int fd = 0; fd < 8; ++fd)
      #pragma unroll
      for (int fq = 0; fq < 2; ++fq){
        acc[fd][fq][0]*=rs[fq]; acc[fd][fq][1]*=rs[fq];
        acc[fd][fq][2]*=rs[fq]; acc[fd][fq][3]*=rs[fq];
      }
    // O^T += V^T @ P^T   (P^T fragments feed B operand directly)
    #pragma unroll
    for (int fd = 0; fd < 8; ++fd){
      int d = fd*16 + l15;
      #pragma unroll
      for (int fk = 0; fk < 4; ++fk){
        int b = (fk*32 + g*8) ^ ((d & 7) << 4);
        s16x4 vf = *(const s16x4*)((const char*)ldsV + d*128 + b);
        #pragma unroll
        for (int fq = 0; fq < 2; ++fq)
          acc[fd][fq] = mfma16x16x16bf(vf, pf[fk][fq], acc[fd][fq]);
      }
    }
    __syncthreads();
  }
  #pragma unroll
  for (int fq = 0; fq < 2; ++fq){
    l_[fq] += __shfl_xor(l_[fq], 16);
    l_[fq] += __shfl_xor(l_[fq], 32);
  }
  const int64_t ob = (int64_t)(h*KSPL + sp) * HDIM * QPAD;
  #pragma unroll
  for (int fd = 0; fd < 8; ++fd)
    #pragma unroll
    for (int fq = 0; fq < 2; ++fq)
      #pragma unroll
      for (int rr = 0; rr < 4; ++rr){
        int d = fd*16 + g*4 + rr;
        int q = qbase + fq*16 + l15;
        OPT[ob + (int64_t)d*QPAD + q] = acc[fd][fq][rr];
      }
  if (g == 0){
    #pragma unroll
    for (int fq = 0; fq < 2; ++fq){
      int q = qbase + fq*16 + l15;
      Mb[(h*KSPL + sp)*QPAD + q] = m_[fq];
      Lb[(h*KSPL + sp)*QPAD + q] = l_[fq];
    }
  }
}

// ---------------- kernel 7: split-K merge -> Ob bf16 [tok][1536] ----------------
__global__ __launch_bounds__(256) void k_merge(const float* __restrict__ OPT, const float* __restrict__ Mb,
       const float* __restrict__ Lb, short* __restrict__ Ob){
  __shared__ float lds[64][130];
  const int qb = blockIdx.x, h = blockIdx.y;
  const int q0 = qb*64;
  const int t = threadIdx.x;
  const int q = t & 63;
  float wsp[KSPL];
  {
    float mm[KSPL], M = -1e30f;
    #pragma unroll
    for (int s = 0; s < KSPL; ++s){ mm[s] = Mb[(h*KSPL+s)*QPAD + q0 + q]; M = fmaxf(M, mm[s]); }
    float D = 0.f;
    #pragma unroll
    for (int s = 0; s < KSPL; ++s){ wsp[s] = __expf(mm[s] - M); D += wsp[s]*Lb[(h*KSPL+s)*QPAD + q0 + q]; }
    float inv = 1.f / D;
    #pragma unroll
    for (int s = 0; s < KSPL; ++s) wsp[s] *= inv;
  }
  for (int i = 0; i < 32; ++i){
    int d = i*4 + (t >> 6);
    float a = 0.f;
    #pragma unroll
    for (int s = 0; s < KSPL; ++s)
      a += wsp[s] * OPT[((int64_t)(h*KSPL+s)*HDIM + d)*QPAD + q0 + q];
    lds[q][d] = a;
  }
  __syncthreads();
  for (int i = 0; i < 16; ++i){
    int idx = i*256 + t;
    int qq = idx >> 6, d2 = (idx & 63)*2;
    if (q0 + qq < NTOK){
      *(uint32_t*)(Ob + (int64_t)(q0+qq)*DIMM + h*HDIM + d2) = pack2(lds[qq][d2], lds[qq][d2+1]);
    }
  }
}

extern "C" void kernel_launch(void* const* d_in, const int* in_sizes, int n_in,
                              void* d_out, int out_size, void* d_ws, size_t ws_size,
                              hipStream_t stream){
  const float* x    = (const float*)d_in[0];
  const float* wq   = (const float*)d_in[1];
  const float* bq   = (const float*)d_in[2];
  const float* wk   = (const float*)d_in[3];
  const float* bk   = (const float*)d_in[4];
  const float* wv   = (const float*)d_in[5];
  const float* bv   = (const float*)d_in[6];
  const float* wo   = (const float*)d_in[7];
  const float* bo   = (const float*)d_in[8];
  const float* gq   = (const float*)d_in[9];
  const float* gk   = (const float*)d_in[10];
  const float* fcos = (const float*)d_in[11];
  const float* fsin = (const float*)d_in[12];
  const float* cache_k = (const float*)d_in[13];
  const float* cache_v = (const float*)d_in[14];
  float* out = (float*)d_out;

  char* ws = (char*)d_ws;
  size_t off = 0;
  auto alloc = [&](size_t bytes){ char* p = ws + off; off += (bytes + 255) & ~(size_t)255; return p; };
  float* qkv  = (float*)alloc(33030144);   // union: qkv f32 [1664][4608] | OPT f32 [12][3][128][1792]
  float* OPT  = qkv;
  short* xb   = (short*)alloc(5111808);    // union: xb bf16 [1664][1536] | Ob
  short* Ob   = xb;
  short* Wqkv = (short*)alloc(14155776);   // bf16 [4608][1536]
  short* Wo   = (short*)alloc(4718592);    // bf16 [1536][1536]
  short* Qb   = (short*)alloc(5505024);    // bf16 [12][1792][128]
  short* Kb   = (short*)alloc(33619968);   // bf16 [12][10944][128]
  short* Vt   = (short*)alloc(33619968);   // bf16 [12][128][10944]
  short* Vtmp = (short*)alloc(4792320);    // bf16 [1560][1536]
  float* Mb   = (float*)alloc(258048);     // f32 [12][3][1792]
  float* Lb   = (float*)alloc(258048);
  if (ws_size < off) return;               // insufficient workspace -> loud failure

  k_conv_misc<<<dim3(2048), dim3(256), 0, stream>>>(x, wq, wk, wv, wo, xb, Wqkv, Wo);
  k_conv_k<<<dim3(2048), dim3(256), 0, stream>>>(cache_k, Kb);
  k_gemm<<<dim3(36, 13), dim3(256), 0, stream>>>(xb, Wqkv, qkv, (const float*)nullptr, NQKV, DIMM, MPAD);
  k_epi<<<dim3(NTOK), dim3(256), 0, stream>>>(qkv, bq, bk, bv, gq, gk, fcos, fsin, Qb, Kb, Vtmp);
  k_conv_v<<<dim3(171, 12), dim3(256), 0, stream>>>(cache_v, Vtmp, Vt);
  k_attn<<<dim3(7, KSPL, NHEADS), dim3(512), 0, stream>>>(Qb, Kb, Vt, OPT, Mb, Lb);
  k_merge<<<dim3(25, NHEADS), dim3(256), 0, stream>>>(OPT, Mb, Lb, Ob);
  k_gemm<<<dim3(12, 13), dim3(256), 0, stream>>>(Ob, Wo, out, bo, DIMM, DIMM, NTOK);
}